// Round 9
// baseline (401.231 us; speedup 1.0000x reference)
//
#include <hip/hip_runtime.h>
#include <hip/hip_bf16.h>

#define NN 50000
#define EE 800000
#define LOG2E 1.44269504088896340736f
#define GB1 1564   // gemm1 blocks in fused k_sg: 4 * ceil(NN/128) = 4*391

// NOTE: harness materializes integer inputs as int32 -> edge_index is const int*.
// NOTE (r7): fp32 scatter atomics = ~80us atomic-latency wall. Avoided.
// NOTE (r9): CSR holds real edges only; self-loop handled inline in agg kernels.
// NOTE (r10-r16): EVERY agg schedule pins at 77-88us (~10.4G random bursts/s
//   beyond-L2). Bytes/occupancy/depth don't move it. Aggs floor ~150us combined.
// NOTE (r18): accounting: sum of per-kernel work ~200us vs 331 measured ->
//   ~130us = 11 dispatches x ~10-12us launch overhead (matches rocprof.md and
//   every "added a kernel, lost 25us" round). This round: 11 -> 7 dispatches:
//   scans 3->1 (single-WG scan), scatter+gemm1 fused (block-split), castx back
//   in prep (bf16 gemm1 = proven r2 config).

typedef short bf16x8 __attribute__((ext_vector_type(8)));
typedef float f32x4  __attribute__((ext_vector_type(4)));

__device__ __forceinline__ unsigned short f2bf(float f) {
    unsigned b = __float_as_uint(f);
    b += 0x7fffu + ((b >> 16) & 1u);           // RNE
    return (unsigned short)(b >> 16);
}
// dword holding two bf16 -> two floats (1 shl + 1 and)
__device__ __forceinline__ float2 bfpair(unsigned u) {
    return make_float2(__uint_as_float(u << 16), __uint_as_float(u & 0xffff0000u));
}

// ---------------- fused prep: v-proj + Wt casts + hist/rank + x cast ----------
// block 0: v ; [1,256]: Wt ; [257,3381]: hist+rank ; [3382,9631]: castx
// v is pre-scaled by log2e (alphas live in exp2 domain downstream).
__global__ void k_prep(const float* __restrict__ We1, const float* __restrict__ ae1,
                       const float* __restrict__ We2, const float* __restrict__ ae2,
                       float* __restrict__ v,
                       const float* __restrict__ W1, unsigned short* __restrict__ W1t,
                       const float* __restrict__ W2, unsigned short* __restrict__ W2t,
                       const int* __restrict__ ei, int* __restrict__ idg,
                       int* __restrict__ rank,
                       const float* __restrict__ x, unsigned short* __restrict__ xb) {
    int bid = blockIdx.x, t = threadIdx.x;
    if (bid == 0) {
        if (t < 8) {            // layer1: c=t>>2, h=t&3 -> v[c*4+h]
            int c = t >> 2, h = t & 3;
            float s = 0.f;
            for (int d = 0; d < 64; d++) s += We1[c * 256 + h * 64 + d] * ae1[h * 64 + d];
            v[c * 4 + h] = s * LOG2E;
        } else if (t < 10) {    // layer2: c=t-8 -> v[8+c]
            int c = t - 8;
            float s = 0.f;
            for (int d = 0; d < 128; d++) s += We2[c * 128 + d] * ae2[d];
            v[8 + c] = s * LOG2E;
        }
    } else if (bid <= 256) {
        int idx = (bid - 1) * 256 + t;
        if (idx < 32768) {                 // W1: 128x256 -> 256x128
            int k = idx >> 8, n = idx & 255;
            W1t[n * 128 + k] = f2bf(W1[idx]);
        } else {                           // W2: 256x128 -> 128x256
            int i = idx - 32768;
            int k = i >> 7, n = i & 127;
            W2t[n * 256 + k] = f2bf(W2[i]);
        }
    } else if (bid <= 256 + 3125) {
        int e = (bid - 257) * 256 + t;
        if (e < EE) rank[e] = atomicAdd(&idg[ei[EE + e]], 1);
    } else {
        int i = (bid - 3382) * 256 + t;
        if (i < NN * 128 / 4) {
            float4 vv = ((const float4*)x)[i];
            ushort4 o;
            o.x = f2bf(vv.x); o.y = f2bf(vv.y); o.z = f2bf(vv.z); o.w = f2bf(vv.w);
            ((ushort4*)xb)[i] = o;
        }
    }
}

// ---------------- CSR build: single-workgroup exclusive scan ------------------
// 1024 threads x 49 elems; two-pass (sum, LDS scan, re-read+write). Replaces
// the 3-dispatch scan chain (~30us of launch overhead) with one ~4us kernel.
__global__ __launch_bounds__(1024) void k_scanA(const int* __restrict__ idg,
                                                int* __restrict__ rowptr) {
    __shared__ int sh[1024];
    int t = threadIdx.x;
    int base = t * 49;
    int s = 0;
    for (int j = 0; j < 49; j++) {
        int i = base + j;
        s += (i < NN) ? idg[i] : 0;
    }
    sh[t] = s;
    __syncthreads();
    for (int off = 1; off < 1024; off <<= 1) {
        int a = (t >= off) ? sh[t - off] : 0;
        __syncthreads();
        sh[t] += a;
        __syncthreads();
    }
    int run = sh[t] - s;                   // exclusive prefix of this chunk
    for (int j = 0; j < 49; j++) {
        int i = base + j;
        if (i < NN) {
            int val = idg[i];
            rowptr[i] = run;
            run += val;
        }
    }
    if (t == 1023) rowptr[NN] = sh[1023];  // == EE
}

// ---------------- GEMM body (device fn): MFMA bf16 + fused attn scalars -------
// C[M,N] = A[M,K] @ Bt[N,K]^T (bf16 out). Per block: 128 rows x NT*16 cols.
// asrc/adst epilogue outputs scaled by log2e (consumed in exp2 domain).
template <int K, int NT, int H>
__device__ __forceinline__ void gemm_body(int bx, int by,
                                          const unsigned short* __restrict__ A,
                                          const unsigned short* __restrict__ Bt,
                                          unsigned short* __restrict__ C,
                                          const float* __restrict__ avs,
                                          const float* __restrict__ avd,
                                          float* __restrict__ asrc,
                                          float* __restrict__ adst,
                                          int M, int N) {
    int wave = threadIdx.x >> 6, lane = threadIdx.x & 63;
    int l16 = lane & 15, quad = lane >> 4;
    int m0 = by * 128 + wave * 32;
    int n0 = bx * (NT * 16);

    f32x4 acc[2][NT];
    #pragma unroll
    for (int mt = 0; mt < 2; mt++)
        #pragma unroll
        for (int nt = 0; nt < NT; nt++)
            acc[mt][nt] = (f32x4){0.f, 0.f, 0.f, 0.f};

    int ar0 = min(m0 + l16, M - 1);
    int ar1 = min(m0 + 16 + l16, M - 1);
    const unsigned short* a0 = A + (size_t)ar0 * K + quad * 8;
    const unsigned short* a1 = A + (size_t)ar1 * K + quad * 8;
    const unsigned short* bp = Bt + (size_t)(n0 + l16) * K + quad * 8;

    #pragma unroll
    for (int k0 = 0; k0 < K; k0 += 32) {
        bf16x8 af0 = *(const bf16x8*)(a0 + k0);
        bf16x8 af1 = *(const bf16x8*)(a1 + k0);
        #pragma unroll
        for (int nt = 0; nt < NT; nt++) {
            bf16x8 bf = *(const bf16x8*)(bp + (size_t)nt * 16 * K + k0);
            acc[0][nt] = __builtin_amdgcn_mfma_f32_16x16x32_bf16(af0, bf, acc[0][nt], 0, 0, 0);
            acc[1][nt] = __builtin_amdgcn_mfma_f32_16x16x32_bf16(af1, bf, acc[1][nt], 0, 0, 0);
        }
    }

    // C store. C/D layout: col = l16, row = quad*4 + reg
    #pragma unroll
    for (int mt = 0; mt < 2; mt++)
        #pragma unroll
        for (int reg = 0; reg < 4; reg++) {
            int row = m0 + mt * 16 + quad * 4 + reg;
            if (row < M) {
                #pragma unroll
                for (int nt = 0; nt < NT; nt++)
                    C[(size_t)row * N + n0 + nt * 16 + l16] = f2bf(acc[mt][nt][reg]);
            }
        }

    // fused attn scalars: asrc/adst[row, head] from fp32 acc (log2e-scaled)
    float ws[NT], wd[NT];
    #pragma unroll
    for (int nt = 0; nt < NT; nt++) {
        ws[nt] = avs[n0 + nt * 16 + l16] * LOG2E;
        wd[nt] = avd[n0 + nt * 16 + l16] * LOG2E;
    }
    int hh = n0 >> 6;          // head index (layer1: bx; layer2: 0)
    #pragma unroll
    for (int mt = 0; mt < 2; mt++)
        #pragma unroll
        for (int reg = 0; reg < 4; reg++) {
            int row = m0 + mt * 16 + quad * 4 + reg;
            float s1 = 0.f, s2 = 0.f;
            #pragma unroll
            for (int nt = 0; nt < NT; nt++) {
                float c = acc[mt][nt][reg];
                s1 += c * ws[nt];
                s2 += c * wd[nt];
            }
            #pragma unroll
            for (int off = 1; off < 16; off <<= 1) {
                s1 += __shfl_xor(s1, off);
                s2 += __shfl_xor(s2, off);
            }
            if (l16 == 0 && row < M) {
                asrc[row * H + hh] = s1;
                adst[row * H + hh] = s2;
            }
        }
}

// ---------------- fused dispatch: gemm1 (blocks [0,GB1)) + scatter ------------
// Both depend only on prep+scanA. Overlaps MFMA-heavy gemm1 with the
// latency-bound scatter; saves one dispatch (~10us).
__global__ __launch_bounds__(256) void k_sg(const unsigned short* __restrict__ xb,
                       const unsigned short* __restrict__ W1t,
                       unsigned short* __restrict__ h1b,
                       const float* __restrict__ as1, const float* __restrict__ ad1,
                       float* __restrict__ asrc1, float* __restrict__ adst1,
                       const int* __restrict__ ei, const float* __restrict__ eattr,
                       const int* __restrict__ rowptr, const int* __restrict__ rank,
                       int2* __restrict__ slot) {
    int bid = blockIdx.x;
    if (bid < GB1) {
        gemm_body<128, 4, 4>(bid & 3, bid >> 2, xb, W1t, h1b, as1, ad1,
                             asrc1, adst1, NN, 256);
    } else {
        int e = (bid - GB1) * 256 + threadIdx.x;
        if (e >= EE) return;
        int s = ei[e], d = ei[EE + e];
        int p = rowptr[d] + rank[e];
        float2 a = ((const float2*)eattr)[e];
        unsigned a0 = f2bf(a.x), a1 = f2bf(a.y);
        slot[p] = make_int2(s, (int)(a0 | (a1 << 16)));
    }
}

// ---------------- layer2 GEMM wrapper -----------------------------------------
__global__ __launch_bounds__(256) void k_gemm2(const unsigned short* __restrict__ A,
                       const unsigned short* __restrict__ Bt,
                       unsigned short* __restrict__ C,
                       const float* __restrict__ avs, const float* __restrict__ avd,
                       float* __restrict__ asrc, float* __restrict__ adst) {
    gemm_body<256, 8, 1>(0, blockIdx.x, A, Bt, C, avs, avd, asrc, adst, NN, 128);
}

// ---------------- layer1 fused softmax+aggregate+bias+ELU ---------------------
// one wave / node; HALF-wave (32 lanes) per edge, 2 edges per wave iteration.
// Lane hl owns channels [hl*8, hl*8+8) -> exactly one head (hl>>3): one alpha
// chain + one exp per lane per edge. Branchless 2-stage rotating slot prefetch
// (clamped index). exp2-domain alphas. No main-loop shuffles.
__global__ __launch_bounds__(256) void k_agg1(const int* __restrict__ rowptr,
                       const int2* __restrict__ slot, const float* __restrict__ asrc,
                       const float* __restrict__ adst, const float* __restrict__ v,
                       const unsigned short* __restrict__ hb, const float* __restrict__ b1,
                       unsigned short* __restrict__ h2b) {
    int node = blockIdx.x * 4 + (threadIdx.x >> 6);
    if (node >= NN) return;
    int lane = threadIdx.x & 63;
    int h2 = lane >> 5;          // which edge of the pair
    int hl = lane & 31;          // channel-lane: owns ch [hl*8, hl*8+8)
    int hd = hl >> 3;            // head owning this lane's channels
    int beg = rowptr[node], end = rowptr[node + 1];
    float pd = adst[node * 4 + hd];
    float vh0 = v[hd], vh1 = v[4 + hd];
    float acc[8] = {};
    float den = 0.f, s0 = 0.f, s1 = 0.f;
    const unsigned short* hbq = hb + hl * 8;

    int cnt = end - beg;
    int safeLast = max(end - 1, 0);
    int mend = beg + (cnt & ~1);

    int2 sl0 = slot[min(beg + h2, safeLast)];
    int2 sl1 = slot[min(beg + 2 + h2, safeLast)];

    auto body = [&](int2 cur) {
        int s = cur.x;
        float2 a = bfpair((unsigned)cur.y);
        float al = asrc[s * 4 + hd] + pd + a.x * vh0 + a.y * vh1;
        al = (al > 0.f) ? al : 0.2f * al;
        float e = __builtin_amdgcn_exp2f(al);
        s0 += a.x; s1 += a.y; den += e;
        uint4 r = *(const uint4*)(hbq + (size_t)s * 256);
        float2 p;
        p = bfpair(r.x); acc[0] += e * p.x; acc[1] += e * p.y;
        p = bfpair(r.y); acc[2] += e * p.x; acc[3] += e * p.y;
        p = bfpair(r.z); acc[4] += e * p.x; acc[5] += e * p.y;
        p = bfpair(r.w); acc[6] += e * p.x; acc[7] += e * p.y;
    };

    #pragma unroll 2
    for (int pb = beg; pb < mend; pb += 2) {
        int2 cur = sl0;
        sl0 = sl1;
        sl1 = slot[min(pb + 4 + h2, safeLast)];
        body(cur);
    }
    if (h2 == 0 && mend < end) body(sl0);   // odd tail: half 0 only

    // cross-half reductions (only shuffles in the kernel)
    #pragma unroll
    for (int k = 0; k < 8; k++) acc[k] += __shfl_down(acc[k], 32);
    den += __shfl_xor(den, 32);
    s0  += __shfl_xor(s0, 32);
    s1  += __shfl_xor(s1, 32);

    // self-loop: mean attrs over real edges (0 if none)
    float dg = fmaxf((float)cnt, 1.0f);
    float als = asrc[node * 4 + hd] + pd + (s0 / dg) * vh0 + (s1 / dg) * vh1;
    als = (als > 0.f) ? als : 0.2f * als;
    float exs = __builtin_amdgcn_exp2f(als);
    den += exs;

    if (h2 == 0) {
        uint4 r = *(const uint4*)(hbq + (size_t)node * 256);
        float2 p;
        p = bfpair(r.x); acc[0] += exs * p.x; acc[1] += exs * p.y;
        p = bfpair(r.y); acc[2] += exs * p.x; acc[3] += exs * p.y;
        p = bfpair(r.z); acc[4] += exs * p.x; acc[5] += exs * p.y;
        p = bfpair(r.w); acc[6] += exs * p.x; acc[7] += exs * p.y;
        float inv = 1.f / (den + 1e-16f);
        short ov[8];
        #pragma unroll
        for (int k = 0; k < 8; k++) {
            float va = acc[k] * inv + b1[hl * 8 + k];
            va = (va > 0.f) ? va : __expf(va) - 1.f;   // ELU (natural e)
            ov[k] = (short)f2bf(va);
        }
        bf16x8 o8 = {ov[0], ov[1], ov[2], ov[3], ov[4], ov[5], ov[6], ov[7]};
        *(bf16x8*)(h2b + (size_t)node * 256 + hl * 8) = o8;
    }
}

// ---------------- layer2 fused softmax+aggregate+bias (H=1, 128ch, fp32 out) --
// quarter-wave per edge (full 256B row per 16 lanes); rotating clamped slot
// prefetch; exp2-domain alphas.
__global__ __launch_bounds__(256) void k_agg2(const int* __restrict__ rowptr,
                       const int2* __restrict__ slot, const float* __restrict__ asrc,
                       const float* __restrict__ adst, const float* __restrict__ v,
                       const unsigned short* __restrict__ gb, const float* __restrict__ b2,
                       float* __restrict__ outp) {
    int node = blockIdx.x * 4 + (threadIdx.x >> 6);
    if (node >= NN) return;
    int lane = threadIdx.x & 63;
    int q  = lane >> 4;          // edge-in-group
    int ql = lane & 15;          // channel-lane (8 ch each)
    int beg = rowptr[node], end = rowptr[node + 1];
    float ad = adst[node];
    float v0 = v[0], v1 = v[1];
    float acc[8] = {};
    float den = 0.f, s0 = 0.f, s1 = 0.f;
    const unsigned short* gbq = gb + ql * 8;

    int cnt = end - beg;
    int safeLast = max(end - 1, 0);
    int mend = beg + (cnt & ~3);

    int2 sl0 = slot[min(beg + q, safeLast)];
    int2 sl1 = slot[min(beg + 4 + q, safeLast)];

    auto body = [&](int2 cur) {
        int s = cur.x;
        float2 a = bfpair((unsigned)cur.y);
        float al = asrc[s] + ad + a.x * v0 + a.y * v1;
        al = (al > 0.f) ? al : 0.2f * al;
        float e = __builtin_amdgcn_exp2f(al);
        s0 += a.x; s1 += a.y; den += e;
        uint4 r = *(const uint4*)(gbq + (size_t)s * 128);
        float2 p;
        p = bfpair(r.x); acc[0] += e * p.x; acc[1] += e * p.y;
        p = bfpair(r.y); acc[2] += e * p.x; acc[3] += e * p.y;
        p = bfpair(r.z); acc[4] += e * p.x; acc[5] += e * p.y;
        p = bfpair(r.w); acc[6] += e * p.x; acc[7] += e * p.y;
    };

    #pragma unroll 2
    for (int pb = beg; pb < mend; pb += 4) {
        int2 cur = sl0;
        sl0 = sl1;
        sl1 = slot[min(pb + 8 + q, safeLast)];
        body(cur);
    }
    if (mend + q < end) body(sl0);          // tail edges

    #pragma unroll
    for (int k = 0; k < 8; k++) {
        acc[k] += __shfl_down(acc[k], 32);
        acc[k] += __shfl_down(acc[k], 16);
    }
    den += __shfl_xor(den, 16); den += __shfl_xor(den, 32);
    s0  += __shfl_xor(s0, 16);  s0  += __shfl_xor(s0, 32);
    s1  += __shfl_xor(s1, 16);  s1  += __shfl_xor(s1, 32);

    // self-loop epilogue
    float dg = fmaxf((float)cnt, 1.0f);
    float als = asrc[node] + ad + (s0 / dg) * v0 + (s1 / dg) * v1;
    als = (als > 0.f) ? als : 0.2f * als;
    float exs = __builtin_amdgcn_exp2f(als);
    den += exs;

    if (q == 0) {
        uint4 r = *(const uint4*)(gbq + (size_t)node * 128);
        float2 p;
        p = bfpair(r.x); acc[0] += exs * p.x; acc[1] += exs * p.y;
        p = bfpair(r.y); acc[2] += exs * p.x; acc[3] += exs * p.y;
        p = bfpair(r.z); acc[4] += exs * p.x; acc[5] += exs * p.y;
        p = bfpair(r.w); acc[6] += exs * p.x; acc[7] += exs * p.y;
        float inv = 1.f / (den + 1e-16f);
        float4 o0, o1;
        o0.x = acc[0] * inv + b2[ql * 8 + 0];
        o0.y = acc[1] * inv + b2[ql * 8 + 1];
        o0.z = acc[2] * inv + b2[ql * 8 + 2];
        o0.w = acc[3] * inv + b2[ql * 8 + 3];
        o1.x = acc[4] * inv + b2[ql * 8 + 4];
        o1.y = acc[5] * inv + b2[ql * 8 + 5];
        o1.z = acc[6] * inv + b2[ql * 8 + 6];
        o1.w = acc[7] * inv + b2[ql * 8 + 7];
        *(float4*)(outp + (size_t)node * 128 + ql * 8)     = o0;
        *(float4*)(outp + (size_t)node * 128 + ql * 8 + 4) = o1;
    }
}

extern "C" void kernel_launch(void* const* d_in, const int* in_sizes, int n_in,
                              void* d_out, int out_size, void* d_ws, size_t ws_size,
                              hipStream_t stream) {
    const float* x     = (const float*)d_in[0];
    const int*   ei    = (const int*)d_in[1];      // int32 on device
    const float* eattr = (const float*)d_in[2];
    const float* W1    = (const float*)d_in[3];
    const float* We1   = (const float*)d_in[4];
    const float* as1   = (const float*)d_in[5];
    const float* ad1   = (const float*)d_in[6];
    const float* ae1   = (const float*)d_in[7];
    const float* b1    = (const float*)d_in[8];
    const float* W2    = (const float*)d_in[9];
    const float* We2   = (const float*)d_in[10];
    const float* as2   = (const float*)d_in[11];
    const float* ad2   = (const float*)d_in[12];
    const float* ae2   = (const float*)d_in[13];
    const float* b2    = (const float*)d_in[14];
    float* out = (float*)d_out;

    // ---- workspace carve ----
    int* idg    = (int*)d_ws;                      // NN
    int* rank   = idg + NN;                        // EE
    int* rowptr = rank + EE;                       // NN+16
    int* bsum   = rowptr + NN + 16;                // 32 (unused, kept for layout)
    int* boff   = bsum + 32;                       // 32 (unused)
    int2* slot  = (int2*)(boff + 32);              // EE (8B-aligned)
    float* asrc1 = (float*)(slot + EE);            // 4*NN
    float* adst1 = asrc1 + 4 * NN;                 // 4*NN
    float* asrc2 = adst1 + 4 * NN;                 // NN
    float* adst2 = asrc2 + NN;                     // NN
    float* vbuf  = adst2 + NN;                     // 64
    unsigned short* ub = (unsigned short*)(((uintptr_t)(vbuf + 64) + 63) & ~(uintptr_t)63);
    unsigned short* x_bf  = ub;                      // NN*128
    unsigned short* W1t   = x_bf + (size_t)NN * 128; // 256*128
    unsigned short* W2t   = W1t + 32768;             // 128*256
    unsigned short* h1_bf = W2t + 32768;             // NN*256
    unsigned short* h2_bf = h1_bf + (size_t)NN * 256;// NN*256
    unsigned short* g2_bf = h2_bf + (size_t)NN * 256;// NN*128

    hipMemsetAsync(idg, 0, (size_t)NN * sizeof(int), stream);

    // prep (v, Wt casts, degree hist + rank, x cast)
    k_prep<<<9632, 256, 0, stream>>>(We1, ae1, We2, ae2, vbuf, W1, W1t, W2, W2t,
                                     ei, idg, rank, x, x_bf);
    // CSR rowptr: single-workgroup scan (replaces 3 dispatches)
    k_scanA<<<1, 1024, 0, stream>>>(idg, rowptr);

    // fused: gemm1 (fused attn scalars) + scatter
    k_sg<<<GB1 + 3125, 256, 0, stream>>>(x_bf, W1t, h1_bf, as1, ad1,
                                         asrc1, adst1, ei, eattr, rowptr, rank, slot);

    // ---- layer 1 aggregate ----
    k_agg1<<<(NN + 3) / 4, 256, 0, stream>>>(rowptr, slot, asrc1, adst1, vbuf,
                                             h1_bf, b1, h2_bf);

    // ---- layer 2 ----
    k_gemm2<<<(NN + 127) / 128, 256, 0, stream>>>(h2_bf, W2t, g2_bf, as2, ad2,
                                                  asrc2, adst2);
    k_agg2<<<(NN + 3) / 4, 256, 0, stream>>>(rowptr, slot, asrc2, adst2, vbuf + 8,
                                             g2_bf, b2, out);
}

// Round 10
// 305.518 us; speedup vs baseline: 1.3133x; 1.3133x over previous
//
#include <hip/hip_runtime.h>
#include <hip/hip_bf16.h>

#define NN 50000
#define EE 800000
#define SCAN_B 2048
#define NB ((NN + SCAN_B - 1) / SCAN_B)   // 25 scan blocks
#define LOG2E 1.44269504088896340736f
#define GB1 1564   // gemm1 blocks in fused k_sg: 4 * ceil(NN/128) = 4*391

// NOTE: harness materializes integer inputs as int32 -> edge_index is const int*.
// NOTE (r7): fp32 scatter atomics = ~80us atomic-latency wall. Avoided.
// NOTE (r9): CSR holds real edges only; self-loop handled inline in agg kernels.
// NOTE (r10-r16): EVERY agg schedule pins at 77-88us (~10.4G random bursts/s
//   beyond-L2). Bytes/occupancy/depth don't move it. Aggs floor ~150us combined.
// NOTE (r18): single-WG scan = 93us (one CU, latency-serialized). NEVER shrink
//   a 100K-elem pass to one workgroup; ~10us dispatch < ~90us single-CU latency.
// NOTE (r19): multi-block scan restored; scan2 folded into scan1 via last-block
//   ticket (threadfence + atomicAdd, no spin). 8 dispatches total; k_sg
//   (gemm1+scatter block-split fusion) kept from r18.

typedef short bf16x8 __attribute__((ext_vector_type(8)));
typedef float f32x4  __attribute__((ext_vector_type(4)));

__device__ __forceinline__ unsigned short f2bf(float f) {
    unsigned b = __float_as_uint(f);
    b += 0x7fffu + ((b >> 16) & 1u);           // RNE
    return (unsigned short)(b >> 16);
}
// dword holding two bf16 -> two floats (1 shl + 1 and)
__device__ __forceinline__ float2 bfpair(unsigned u) {
    return make_float2(__uint_as_float(u << 16), __uint_as_float(u & 0xffff0000u));
}

// ---------------- fused prep: v-proj + Wt casts + hist/rank + x cast ----------
// block 0: v ; [1,256]: Wt ; [257,3381]: hist+rank ; [3382,9631]: castx
// v is pre-scaled by log2e (alphas live in exp2 domain downstream).
__global__ void k_prep(const float* __restrict__ We1, const float* __restrict__ ae1,
                       const float* __restrict__ We2, const float* __restrict__ ae2,
                       float* __restrict__ v,
                       const float* __restrict__ W1, unsigned short* __restrict__ W1t,
                       const float* __restrict__ W2, unsigned short* __restrict__ W2t,
                       const int* __restrict__ ei, int* __restrict__ idg,
                       int* __restrict__ rank,
                       const float* __restrict__ x, unsigned short* __restrict__ xb) {
    int bid = blockIdx.x, t = threadIdx.x;
    if (bid == 0) {
        if (t < 8) {            // layer1: c=t>>2, h=t&3 -> v[c*4+h]
            int c = t >> 2, h = t & 3;
            float s = 0.f;
            for (int d = 0; d < 64; d++) s += We1[c * 256 + h * 64 + d] * ae1[h * 64 + d];
            v[c * 4 + h] = s * LOG2E;
        } else if (t < 10) {    // layer2: c=t-8 -> v[8+c]
            int c = t - 8;
            float s = 0.f;
            for (int d = 0; d < 128; d++) s += We2[c * 128 + d] * ae2[d];
            v[8 + c] = s * LOG2E;
        }
    } else if (bid <= 256) {
        int idx = (bid - 1) * 256 + t;
        if (idx < 32768) {                 // W1: 128x256 -> 256x128
            int k = idx >> 8, n = idx & 255;
            W1t[n * 128 + k] = f2bf(W1[idx]);
        } else {                           // W2: 256x128 -> 128x256
            int i = idx - 32768;
            int k = i >> 7, n = i & 127;
            W2t[n * 256 + k] = f2bf(W2[i]);
        }
    } else if (bid <= 256 + 3125) {
        int e = (bid - 257) * 256 + t;
        if (e < EE) rank[e] = atomicAdd(&idg[ei[EE + e]], 1);
    } else {
        int i = (bid - 3382) * 256 + t;
        if (i < NN * 128 / 4) {
            float4 vv = ((const float4*)x)[i];
            ushort4 o;
            o.x = f2bf(vv.x); o.y = f2bf(vv.y); o.z = f2bf(vv.z); o.w = f2bf(vv.w);
            ((ushort4*)xb)[i] = o;
        }
    }
}

// ---------------- CSR build: scan1 (+ fused scan2 via last-block ticket) ------
__global__ void k_scan12(const int* __restrict__ idg, int* __restrict__ rowptr,
                         int* __restrict__ bsum, int* __restrict__ boff,
                         int* __restrict__ ticket) {
    __shared__ int sh[512];
    int t = threadIdx.x;
    int base = blockIdx.x * SCAN_B + t * 4;
    int v[4]; int s = 0;
    #pragma unroll
    for (int j = 0; j < 4; j++) {
        int i = base + j;
        v[j] = (i < NN) ? idg[i] : 0;
        s += v[j];
    }
    sh[t] = s;
    __syncthreads();
    for (int off = 1; off < 512; off <<= 1) {
        int a = (t >= off) ? sh[t - off] : 0;
        __syncthreads();
        sh[t] += a;
        __syncthreads();
    }
    int run = sh[t] - s;
    #pragma unroll
    for (int j = 0; j < 4; j++) {
        int i = base + j;
        if (i < NN) rowptr[i] = run;
        run += v[j];
    }
    if (t == 511) bsum[blockIdx.x] = sh[511];
    __syncthreads();
    __threadfence();
    if (t == 0) {
        int done = atomicAdd(ticket, 1);
        if (done == NB - 1) {              // last block: do scan2's work
            __threadfence();
            int acc = 0;
            for (int b = 0; b < NB; b++) { boff[b] = acc; acc += bsum[b]; }
            rowptr[NN] = acc;              // == EE
        }
    }
}

__global__ void k_scan3(int* __restrict__ rowptr, const int* __restrict__ boff) {
    int t = threadIdx.x;
    int i = blockIdx.x * SCAN_B + t * 4;
    int off = boff[blockIdx.x];
    #pragma unroll
    for (int j = 0; j < 4; j++)
        if (i + j < NN) rowptr[i + j] += off;
}

// ---------------- GEMM body (device fn): MFMA bf16 + fused attn scalars -------
// C[M,N] = A[M,K] @ Bt[N,K]^T (bf16 out). Per block: 128 rows x NT*16 cols.
// asrc/adst epilogue outputs scaled by log2e (consumed in exp2 domain).
template <int K, int NT, int H>
__device__ __forceinline__ void gemm_body(int bx, int by,
                                          const unsigned short* __restrict__ A,
                                          const unsigned short* __restrict__ Bt,
                                          unsigned short* __restrict__ C,
                                          const float* __restrict__ avs,
                                          const float* __restrict__ avd,
                                          float* __restrict__ asrc,
                                          float* __restrict__ adst,
                                          int M, int N) {
    int wave = threadIdx.x >> 6, lane = threadIdx.x & 63;
    int l16 = lane & 15, quad = lane >> 4;
    int m0 = by * 128 + wave * 32;
    int n0 = bx * (NT * 16);

    f32x4 acc[2][NT];
    #pragma unroll
    for (int mt = 0; mt < 2; mt++)
        #pragma unroll
        for (int nt = 0; nt < NT; nt++)
            acc[mt][nt] = (f32x4){0.f, 0.f, 0.f, 0.f};

    int ar0 = min(m0 + l16, M - 1);
    int ar1 = min(m0 + 16 + l16, M - 1);
    const unsigned short* a0 = A + (size_t)ar0 * K + quad * 8;
    const unsigned short* a1 = A + (size_t)ar1 * K + quad * 8;
    const unsigned short* bp = Bt + (size_t)(n0 + l16) * K + quad * 8;

    #pragma unroll
    for (int k0 = 0; k0 < K; k0 += 32) {
        bf16x8 af0 = *(const bf16x8*)(a0 + k0);
        bf16x8 af1 = *(const bf16x8*)(a1 + k0);
        #pragma unroll
        for (int nt = 0; nt < NT; nt++) {
            bf16x8 bf = *(const bf16x8*)(bp + (size_t)nt * 16 * K + k0);
            acc[0][nt] = __builtin_amdgcn_mfma_f32_16x16x32_bf16(af0, bf, acc[0][nt], 0, 0, 0);
            acc[1][nt] = __builtin_amdgcn_mfma_f32_16x16x32_bf16(af1, bf, acc[1][nt], 0, 0, 0);
        }
    }

    // C store. C/D layout: col = l16, row = quad*4 + reg
    #pragma unroll
    for (int mt = 0; mt < 2; mt++)
        #pragma unroll
        for (int reg = 0; reg < 4; reg++) {
            int row = m0 + mt * 16 + quad * 4 + reg;
            if (row < M) {
                #pragma unroll
                for (int nt = 0; nt < NT; nt++)
                    C[(size_t)row * N + n0 + nt * 16 + l16] = f2bf(acc[mt][nt][reg]);
            }
        }

    // fused attn scalars: asrc/adst[row, head] from fp32 acc (log2e-scaled)
    float ws[NT], wd[NT];
    #pragma unroll
    for (int nt = 0; nt < NT; nt++) {
        ws[nt] = avs[n0 + nt * 16 + l16] * LOG2E;
        wd[nt] = avd[n0 + nt * 16 + l16] * LOG2E;
    }
    int hh = n0 >> 6;          // head index (layer1: bx; layer2: 0)
    #pragma unroll
    for (int mt = 0; mt < 2; mt++)
        #pragma unroll
        for (int reg = 0; reg < 4; reg++) {
            int row = m0 + mt * 16 + quad * 4 + reg;
            float s1 = 0.f, s2 = 0.f;
            #pragma unroll
            for (int nt = 0; nt < NT; nt++) {
                float c = acc[mt][nt][reg];
                s1 += c * ws[nt];
                s2 += c * wd[nt];
            }
            #pragma unroll
            for (int off = 1; off < 16; off <<= 1) {
                s1 += __shfl_xor(s1, off);
                s2 += __shfl_xor(s2, off);
            }
            if (l16 == 0 && row < M) {
                asrc[row * H + hh] = s1;
                adst[row * H + hh] = s2;
            }
        }
}

// ---------------- fused dispatch: gemm1 (blocks [0,GB1)) + scatter ------------
// Both depend only on prep+scan. Overlaps MFMA-heavy gemm1 with the
// latency-bound scatter; saves one dispatch (~10us).
__global__ __launch_bounds__(256) void k_sg(const unsigned short* __restrict__ xb,
                       const unsigned short* __restrict__ W1t,
                       unsigned short* __restrict__ h1b,
                       const float* __restrict__ as1, const float* __restrict__ ad1,
                       float* __restrict__ asrc1, float* __restrict__ adst1,
                       const int* __restrict__ ei, const float* __restrict__ eattr,
                       const int* __restrict__ rowptr, const int* __restrict__ rank,
                       int2* __restrict__ slot) {
    int bid = blockIdx.x;
    if (bid < GB1) {
        gemm_body<128, 4, 4>(bid & 3, bid >> 2, xb, W1t, h1b, as1, ad1,
                             asrc1, adst1, NN, 256);
    } else {
        int e = (bid - GB1) * 256 + threadIdx.x;
        if (e >= EE) return;
        int s = ei[e], d = ei[EE + e];
        int p = rowptr[d] + rank[e];
        float2 a = ((const float2*)eattr)[e];
        unsigned a0 = f2bf(a.x), a1 = f2bf(a.y);
        slot[p] = make_int2(s, (int)(a0 | (a1 << 16)));
    }
}

// ---------------- layer2 GEMM wrapper -----------------------------------------
__global__ __launch_bounds__(256) void k_gemm2(const unsigned short* __restrict__ A,
                       const unsigned short* __restrict__ Bt,
                       unsigned short* __restrict__ C,
                       const float* __restrict__ avs, const float* __restrict__ avd,
                       float* __restrict__ asrc, float* __restrict__ adst) {
    gemm_body<256, 8, 1>(0, blockIdx.x, A, Bt, C, avs, avd, asrc, adst, NN, 128);
}

// ---------------- layer1 fused softmax+aggregate+bias+ELU ---------------------
// one wave / node; HALF-wave (32 lanes) per edge, 2 edges per wave iteration.
// Lane hl owns channels [hl*8, hl*8+8) -> exactly one head (hl>>3): one alpha
// chain + one exp per lane per edge. Branchless 2-stage rotating slot prefetch
// (clamped index). exp2-domain alphas. No main-loop shuffles.
__global__ __launch_bounds__(256) void k_agg1(const int* __restrict__ rowptr,
                       const int2* __restrict__ slot, const float* __restrict__ asrc,
                       const float* __restrict__ adst, const float* __restrict__ v,
                       const unsigned short* __restrict__ hb, const float* __restrict__ b1,
                       unsigned short* __restrict__ h2b) {
    int node = blockIdx.x * 4 + (threadIdx.x >> 6);
    if (node >= NN) return;
    int lane = threadIdx.x & 63;
    int h2 = lane >> 5;          // which edge of the pair
    int hl = lane & 31;          // channel-lane: owns ch [hl*8, hl*8+8)
    int hd = hl >> 3;            // head owning this lane's channels
    int beg = rowptr[node], end = rowptr[node + 1];
    float pd = adst[node * 4 + hd];
    float vh0 = v[hd], vh1 = v[4 + hd];
    float acc[8] = {};
    float den = 0.f, s0 = 0.f, s1 = 0.f;
    const unsigned short* hbq = hb + hl * 8;

    int cnt = end - beg;
    int safeLast = max(end - 1, 0);
    int mend = beg + (cnt & ~1);

    int2 sl0 = slot[min(beg + h2, safeLast)];
    int2 sl1 = slot[min(beg + 2 + h2, safeLast)];

    auto body = [&](int2 cur) {
        int s = cur.x;
        float2 a = bfpair((unsigned)cur.y);
        float al = asrc[s * 4 + hd] + pd + a.x * vh0 + a.y * vh1;
        al = (al > 0.f) ? al : 0.2f * al;
        float e = __builtin_amdgcn_exp2f(al);
        s0 += a.x; s1 += a.y; den += e;
        uint4 r = *(const uint4*)(hbq + (size_t)s * 256);
        float2 p;
        p = bfpair(r.x); acc[0] += e * p.x; acc[1] += e * p.y;
        p = bfpair(r.y); acc[2] += e * p.x; acc[3] += e * p.y;
        p = bfpair(r.z); acc[4] += e * p.x; acc[5] += e * p.y;
        p = bfpair(r.w); acc[6] += e * p.x; acc[7] += e * p.y;
    };

    #pragma unroll 2
    for (int pb = beg; pb < mend; pb += 2) {
        int2 cur = sl0;
        sl0 = sl1;
        sl1 = slot[min(pb + 4 + h2, safeLast)];
        body(cur);
    }
    if (h2 == 0 && mend < end) body(sl0);   // odd tail: half 0 only

    // cross-half reductions (only shuffles in the kernel)
    #pragma unroll
    for (int k = 0; k < 8; k++) acc[k] += __shfl_down(acc[k], 32);
    den += __shfl_xor(den, 32);
    s0  += __shfl_xor(s0, 32);
    s1  += __shfl_xor(s1, 32);

    // self-loop: mean attrs over real edges (0 if none)
    float dg = fmaxf((float)cnt, 1.0f);
    float als = asrc[node * 4 + hd] + pd + (s0 / dg) * vh0 + (s1 / dg) * vh1;
    als = (als > 0.f) ? als : 0.2f * als;
    float exs = __builtin_amdgcn_exp2f(als);
    den += exs;

    if (h2 == 0) {
        uint4 r = *(const uint4*)(hbq + (size_t)node * 256);
        float2 p;
        p = bfpair(r.x); acc[0] += exs * p.x; acc[1] += exs * p.y;
        p = bfpair(r.y); acc[2] += exs * p.x; acc[3] += exs * p.y;
        p = bfpair(r.z); acc[4] += exs * p.x; acc[5] += exs * p.y;
        p = bfpair(r.w); acc[6] += exs * p.x; acc[7] += exs * p.y;
        float inv = 1.f / (den + 1e-16f);
        short ov[8];
        #pragma unroll
        for (int k = 0; k < 8; k++) {
            float va = acc[k] * inv + b1[hl * 8 + k];
            va = (va > 0.f) ? va : __expf(va) - 1.f;   // ELU (natural e)
            ov[k] = (short)f2bf(va);
        }
        bf16x8 o8 = {ov[0], ov[1], ov[2], ov[3], ov[4], ov[5], ov[6], ov[7]};
        *(bf16x8*)(h2b + (size_t)node * 256 + hl * 8) = o8;
    }
}

// ---------------- layer2 fused softmax+aggregate+bias (H=1, 128ch, fp32 out) --
// quarter-wave per edge (full 256B row per 16 lanes); rotating clamped slot
// prefetch; exp2-domain alphas.
__global__ __launch_bounds__(256) void k_agg2(const int* __restrict__ rowptr,
                       const int2* __restrict__ slot, const float* __restrict__ asrc,
                       const float* __restrict__ adst, const float* __restrict__ v,
                       const unsigned short* __restrict__ gb, const float* __restrict__ b2,
                       float* __restrict__ outp) {
    int node = blockIdx.x * 4 + (threadIdx.x >> 6);
    if (node >= NN) return;
    int lane = threadIdx.x & 63;
    int q  = lane >> 4;          // edge-in-group
    int ql = lane & 15;          // channel-lane (8 ch each)
    int beg = rowptr[node], end = rowptr[node + 1];
    float ad = adst[node];
    float v0 = v[0], v1 = v[1];
    float acc[8] = {};
    float den = 0.f, s0 = 0.f, s1 = 0.f;
    const unsigned short* gbq = gb + ql * 8;

    int cnt = end - beg;
    int safeLast = max(end - 1, 0);
    int mend = beg + (cnt & ~3);

    int2 sl0 = slot[min(beg + q, safeLast)];
    int2 sl1 = slot[min(beg + 4 + q, safeLast)];

    auto body = [&](int2 cur) {
        int s = cur.x;
        float2 a = bfpair((unsigned)cur.y);
        float al = asrc[s] + ad + a.x * v0 + a.y * v1;
        al = (al > 0.f) ? al : 0.2f * al;
        float e = __builtin_amdgcn_exp2f(al);
        s0 += a.x; s1 += a.y; den += e;
        uint4 r = *(const uint4*)(gbq + (size_t)s * 128);
        float2 p;
        p = bfpair(r.x); acc[0] += e * p.x; acc[1] += e * p.y;
        p = bfpair(r.y); acc[2] += e * p.x; acc[3] += e * p.y;
        p = bfpair(r.z); acc[4] += e * p.x; acc[5] += e * p.y;
        p = bfpair(r.w); acc[6] += e * p.x; acc[7] += e * p.y;
    };

    #pragma unroll 2
    for (int pb = beg; pb < mend; pb += 4) {
        int2 cur = sl0;
        sl0 = sl1;
        sl1 = slot[min(pb + 8 + q, safeLast)];
        body(cur);
    }
    if (mend + q < end) body(sl0);          // tail edges

    #pragma unroll
    for (int k = 0; k < 8; k++) {
        acc[k] += __shfl_down(acc[k], 32);
        acc[k] += __shfl_down(acc[k], 16);
    }
    den += __shfl_xor(den, 16); den += __shfl_xor(den, 32);
    s0  += __shfl_xor(s0, 16);  s0  += __shfl_xor(s0, 32);
    s1  += __shfl_xor(s1, 16);  s1  += __shfl_xor(s1, 32);

    // self-loop epilogue
    float dg = fmaxf((float)cnt, 1.0f);
    float als = asrc[node] + ad + (s0 / dg) * v0 + (s1 / dg) * v1;
    als = (als > 0.f) ? als : 0.2f * als;
    float exs = __builtin_amdgcn_exp2f(als);
    den += exs;

    if (q == 0) {
        uint4 r = *(const uint4*)(gbq + (size_t)node * 128);
        float2 p;
        p = bfpair(r.x); acc[0] += exs * p.x; acc[1] += exs * p.y;
        p = bfpair(r.y); acc[2] += exs * p.x; acc[3] += exs * p.y;
        p = bfpair(r.z); acc[4] += exs * p.x; acc[5] += exs * p.y;
        p = bfpair(r.w); acc[6] += exs * p.x; acc[7] += exs * p.y;
        float inv = 1.f / (den + 1e-16f);
        float4 o0, o1;
        o0.x = acc[0] * inv + b2[ql * 8 + 0];
        o0.y = acc[1] * inv + b2[ql * 8 + 1];
        o0.z = acc[2] * inv + b2[ql * 8 + 2];
        o0.w = acc[3] * inv + b2[ql * 8 + 3];
        o1.x = acc[4] * inv + b2[ql * 8 + 4];
        o1.y = acc[5] * inv + b2[ql * 8 + 5];
        o1.z = acc[6] * inv + b2[ql * 8 + 6];
        o1.w = acc[7] * inv + b2[ql * 8 + 7];
        *(float4*)(outp + (size_t)node * 128 + ql * 8)     = o0;
        *(float4*)(outp + (size_t)node * 128 + ql * 8 + 4) = o1;
    }
}

extern "C" void kernel_launch(void* const* d_in, const int* in_sizes, int n_in,
                              void* d_out, int out_size, void* d_ws, size_t ws_size,
                              hipStream_t stream) {
    const float* x     = (const float*)d_in[0];
    const int*   ei    = (const int*)d_in[1];      // int32 on device
    const float* eattr = (const float*)d_in[2];
    const float* W1    = (const float*)d_in[3];
    const float* We1   = (const float*)d_in[4];
    const float* as1   = (const float*)d_in[5];
    const float* ad1   = (const float*)d_in[6];
    const float* ae1   = (const float*)d_in[7];
    const float* b1    = (const float*)d_in[8];
    const float* W2    = (const float*)d_in[9];
    const float* We2   = (const float*)d_in[10];
    const float* as2   = (const float*)d_in[11];
    const float* ad2   = (const float*)d_in[12];
    const float* ae2   = (const float*)d_in[13];
    const float* b2    = (const float*)d_in[14];
    float* out = (float*)d_out;

    // ---- workspace carve ----
    int* idg    = (int*)d_ws;                      // NN
    int* ticket = idg + NN;                        // 16 (zeroed with idg)
    int* rank   = ticket + 16;                     // EE
    int* rowptr = rank + EE;                       // NN+16
    int* bsum   = rowptr + NN + 16;                // 32
    int* boff   = bsum + 32;                       // 32
    int2* slot  = (int2*)(boff + 32);              // EE (8B-aligned)
    float* asrc1 = (float*)(slot + EE);            // 4*NN
    float* adst1 = asrc1 + 4 * NN;                 // 4*NN
    float* asrc2 = adst1 + 4 * NN;                 // NN
    float* adst2 = asrc2 + NN;                     // NN
    float* vbuf  = adst2 + NN;                     // 64
    unsigned short* ub = (unsigned short*)(((uintptr_t)(vbuf + 64) + 63) & ~(uintptr_t)63);
    unsigned short* x_bf  = ub;                      // NN*128
    unsigned short* W1t   = x_bf + (size_t)NN * 128; // 256*128
    unsigned short* W2t   = W1t + 32768;             // 128*256
    unsigned short* h1_bf = W2t + 32768;             // NN*256
    unsigned short* h2_bf = h1_bf + (size_t)NN * 256;// NN*256
    unsigned short* g2_bf = h2_bf + (size_t)NN * 256;// NN*128

    hipMemsetAsync(idg, 0, (size_t)(NN + 16) * sizeof(int), stream);

    // prep (v, Wt casts, degree hist + rank, x cast)
    k_prep<<<9632, 256, 0, stream>>>(We1, ae1, We2, ae2, vbuf, W1, W1t, W2, W2t,
                                     ei, idg, rank, x, x_bf);
    // CSR rowptr: multi-block scan; scan2 folded via last-block ticket
    k_scan12<<<NB, 512, 0, stream>>>(idg, rowptr, bsum, boff, ticket);
    k_scan3<<<NB, 512, 0, stream>>>(rowptr, boff);

    // fused: gemm1 (fused attn scalars) + scatter
    k_sg<<<GB1 + 3125, 256, 0, stream>>>(x_bf, W1t, h1_bf, as1, ad1,
                                         asrc1, adst1, ei, eattr, rowptr, rank, slot);

    // ---- layer 1 aggregate ----
    k_agg1<<<(NN + 3) / 4, 256, 0, stream>>>(rowptr, slot, asrc1, adst1, vbuf,
                                             h1_bf, b1, h2_bf);

    // ---- layer 2 ----
    k_gemm2<<<(NN + 127) / 128, 256, 0, stream>>>(h2_bf, W2t, g2_bf, as2, ad2,
                                                  asrc2, adst2);
    k_agg2<<<(NN + 3) / 4, 256, 0, stream>>>(rowptr, slot, asrc2, adst2, vbuf + 8,
                                             g2_bf, b2, out);
}